// Round 7
// baseline (39.788 us; speedup 1.0000x reference)
//
#include <hip/hip_runtime.h>
#include <hip/hip_fp16.h>
#include <math.h>

#define IN_DIM 256
#define L1_DIM 16

typedef _Float16 f16x8 __attribute__((ext_vector_type(8)));
typedef float f32x4 __attribute__((ext_vector_type(4)));

// ---------------- proj kernel (MFMA f16) ----------------
// GEMM M=n_nodes, N=32 ([w1|w2]), K=256 via mfma_f32_16x16x32_f16.
// Block = 256 = 4 waves, M=64 nodes/block, wave w owns rows 16w..16w+15.
// No LDS, no barrier: lane (q=l>>4, r=l&15) loads its A-fragment directly
// from global; B fragments (both fp16 weight tables) preloaded into VGPRs.
// Trailing 8 blocks convert w*_l2 to fp16 for the edge kernel.
__global__ __launch_bounds__(256) void proj_kernel(
    const float* __restrict__ z,
    const float* __restrict__ w1,     // [256][16]
    const float* __restrict__ w2,
    const float* __restrict__ w1_l2,  // [1000][16]
    const float* __restrict__ w2_l2,
    __half* __restrict__ h1,          // [n_nodes][16] fp16
    __half* __restrict__ h2,
    __half* __restrict__ w1h,
    __half* __restrict__ w2h,
    int n_nodes, int nblocks_proj) {
  // trailing blocks: convert level-2 weight tables to fp16
  if ((int)blockIdx.x >= nblocks_proj) {
    int t0 = ((int)blockIdx.x - nblocks_proj) * 256 + (int)threadIdx.x;
    const int total = 1000 * L1_DIM;  // 16000
    for (int i = t0; i < total; i += 8 * 256) {
      w1h[i] = __float2half(w1_l2[i]);
      w2h[i] = __float2half(w2_l2[i]);
    }
    return;
  }

  const int tid  = (int)threadIdx.x;
  const int lane = tid & 63;
  const int wv   = tid >> 6;      // 0..3
  const int r    = lane & 15;     // A row-in-tile / B col / D col
  const int q    = lane >> 4;     // k-subgroup 0..3
  const int node0 = (int)blockIdx.x * 64;

  // ---- B fragments: k = 32s + 8q + j, col = r ----
  f16x8 bf1[8], bf2[8];
#pragma unroll
  for (int s = 0; s < 8; ++s) {
#pragma unroll
    for (int j = 0; j < 8; ++j) {
      int k = 32 * s + 8 * q + j;
      bf1[s][j] = (_Float16)w1[k * L1_DIM + r];
      bf2[s][j] = (_Float16)w2[k * L1_DIM + r];
    }
  }

  // ---- A row pointer (clamped for tail block) ----
  int arow = node0 + wv * 16 + r;
  int ar = arow < n_nodes ? arow : (n_nodes - 1);
  const float* zrow = z + (size_t)ar * IN_DIM + 8 * q;

  f32x4 acc1 = {0.f, 0.f, 0.f, 0.f};
  f32x4 acc2 = {0.f, 0.f, 0.f, 0.f};

#pragma unroll
  for (int s = 0; s < 8; ++s) {
    float4 lo = *reinterpret_cast<const float4*>(zrow + 32 * s);
    float4 hi = *reinterpret_cast<const float4*>(zrow + 32 * s + 4);
    f16x8 af;
    af[0] = (_Float16)lo.x; af[1] = (_Float16)lo.y;
    af[2] = (_Float16)lo.z; af[3] = (_Float16)lo.w;
    af[4] = (_Float16)hi.x; af[5] = (_Float16)hi.y;
    af[6] = (_Float16)hi.z; af[7] = (_Float16)hi.w;
    acc1 = __builtin_amdgcn_mfma_f32_16x16x32_f16(af, bf1[s], acc1, 0, 0, 0);
    acc2 = __builtin_amdgcn_mfma_f32_16x16x32_f16(af, bf2[s], acc2, 0, 0, 0);
  }

  // ---- D layout: col = r, row = 4q + i -> node = node0 + 16wv + 4q + i ----
#pragma unroll
  for (int i = 0; i < 4; ++i) {
    int node = node0 + wv * 16 + 4 * q + i;
    if (node < n_nodes) {
      h1[(size_t)node * L1_DIM + r] = __float2half(fmaxf(acc1[i], 0.f));
      h2[(size_t)node * L1_DIM + r] = __float2half(fmaxf(acc2[i], 0.f));
    }
  }
}

// ---------------- edge kernel ----------------
// 1 lane per edge: 3 index loads, then 8 independent 16B gathers (one vmcnt
// drain covers all -> deep MLP per lane), 16-dim dot via v_dot2_f32_f16,
// uniform store. h tables fp16 (3.2 MB) L2-resident.
union F4H { float4 f; __half2 h[4]; };

__global__ __launch_bounds__(256) void edge_kernel(
    const int* __restrict__ edge_index,  // [2][n_edges]
    const int* __restrict__ edge_type,   // [n_edges]
    const __half* __restrict__ h1,
    const __half* __restrict__ h2,
    const __half* __restrict__ w1h,      // [1000][16]
    const __half* __restrict__ w2h,
    float* __restrict__ out,
    int n_edges) {
  int e = (int)blockIdx.x * 256 + (int)threadIdx.x;
  if (e >= n_edges) return;

  int src = edge_index[e];
  int dst = edge_index[n_edges + e];
  int t   = edge_type[e];

  const __half* pa = h1  + (size_t)src * L1_DIM;
  const __half* pb = h2  + (size_t)dst * L1_DIM;
  const __half* pu = w1h + (size_t)t   * L1_DIM;
  const __half* pv = w2h + (size_t)t   * L1_DIM;

  F4H a0, a1, b0, b1, u0, u1, v0, v1;
  a0.f = *reinterpret_cast<const float4*>(pa);
  a1.f = *reinterpret_cast<const float4*>(pa + 8);
  b0.f = *reinterpret_cast<const float4*>(pb);
  b1.f = *reinterpret_cast<const float4*>(pb + 8);
  u0.f = *reinterpret_cast<const float4*>(pu);
  u1.f = *reinterpret_cast<const float4*>(pu + 8);
  v0.f = *reinterpret_cast<const float4*>(pv);
  v1.f = *reinterpret_cast<const float4*>(pv + 8);

  float s = 0.f;
#if __has_builtin(__builtin_amdgcn_fdot2)
#pragma unroll
  for (int p = 0; p < 4; ++p) {
    s = __builtin_amdgcn_fdot2(a0.h[p], u0.h[p], s, false);
    s = __builtin_amdgcn_fdot2(a1.h[p], u1.h[p], s, false);
    s = __builtin_amdgcn_fdot2(b0.h[p], v0.h[p], s, false);
    s = __builtin_amdgcn_fdot2(b1.h[p], v1.h[p], s, false);
  }
#else
#pragma unroll
  for (int p = 0; p < 4; ++p) {
    float2 af0 = __half22float2(a0.h[p]), uf0 = __half22float2(u0.h[p]);
    float2 af1 = __half22float2(a1.h[p]), uf1 = __half22float2(u1.h[p]);
    float2 bf0 = __half22float2(b0.h[p]), vf0 = __half22float2(v0.h[p]);
    float2 bf1 = __half22float2(b1.h[p]), vf1 = __half22float2(v1.h[p]);
    s = fmaf(af0.x, uf0.x, s); s = fmaf(af0.y, uf0.y, s);
    s = fmaf(af1.x, uf1.x, s); s = fmaf(af1.y, uf1.y, s);
    s = fmaf(bf0.x, vf0.x, s); s = fmaf(bf0.y, vf0.y, s);
    s = fmaf(bf1.x, vf1.x, s); s = fmaf(bf1.y, vf1.y, s);
  }
#endif

  out[e] = 1.0f / (1.0f + __expf(-s));
}

extern "C" void kernel_launch(void* const* d_in, const int* in_sizes, int n_in,
                              void* d_out, int out_size, void* d_ws, size_t ws_size,
                              hipStream_t stream) {
  const float* z      = (const float*)d_in[0];
  const int* edge_idx = (const int*)d_in[1];
  const int* edge_typ = (const int*)d_in[2];
  const float* w1_l1  = (const float*)d_in[3];
  const float* w1_l2  = (const float*)d_in[4];
  const float* w2_l1  = (const float*)d_in[5];
  const float* w2_l2  = (const float*)d_in[6];
  float* out = (float*)d_out;

  int n_nodes = in_sizes[0] / IN_DIM;
  int n_edges = in_sizes[2];
  int n_l2    = in_sizes[4];      // 1000*16

  __half* h1  = (__half*)d_ws;
  __half* h2  = h1 + (size_t)n_nodes * L1_DIM;
  __half* w1h = h2 + (size_t)n_nodes * L1_DIM;
  __half* w2h = w1h + (size_t)n_l2;

  {
    int nblocks_proj = (n_nodes + 63) / 64;   // 782
    int grid = nblocks_proj + 8;              // +8 blocks: w fp16 convert
    proj_kernel<<<grid, 256, 0, stream>>>(z, w1_l1, w2_l1, w1_l2, w2_l2,
                                          h1, h2, w1h, w2h,
                                          n_nodes, nblocks_proj);
  }
  {
    int block = 256;
    int grid = (n_edges + block - 1) / block;
    edge_kernel<<<grid, block, 0, stream>>>(edge_idx, edge_typ, h1, h2,
                                            w1h, w2h, out, n_edges);
  }
}

// Round 8
// 34.513 us; speedup vs baseline: 1.1529x; 1.1529x over previous
//
#include <hip/hip_runtime.h>
#include <hip/hip_fp16.h>
#include <math.h>

#define IN_DIM 256
#define L1_DIM 16
#define N_ETYPE_MAX 1000

typedef _Float16 f16x8 __attribute__((ext_vector_type(8)));
typedef float f32x4 __attribute__((ext_vector_type(4)));

// ---------------- proj kernel (MFMA f16) ----------------
// GEMM M=n_nodes, N=32 ([w1|w2]), K=256 via mfma_f32_16x16x32_f16.
// Block = 256 = 4 waves, M=64 nodes/block, wave w owns rows 16w..16w+15.
// No LDS, no barrier. Trailing 8 blocks build the INTERLEAVED fp16 level-2
// table wq[t] = [w1_l2[t][0..15] | w2_l2[t][0..15]] (64 B per type).
__global__ __launch_bounds__(256) void proj_kernel(
    const float* __restrict__ z,
    const float* __restrict__ w1,     // [256][16]
    const float* __restrict__ w2,
    const float* __restrict__ w1_l2,  // [1000][16]
    const float* __restrict__ w2_l2,
    __half* __restrict__ h1,          // [n_nodes][16] fp16
    __half* __restrict__ h2,
    __half* __restrict__ wq,          // [n_l2_types][32] interleaved fp16
    int n_nodes, int n_l2, int nblocks_proj) {
  // trailing blocks: build interleaved fp16 level-2 table
  if ((int)blockIdx.x >= nblocks_proj) {
    int t0 = ((int)blockIdx.x - nblocks_proj) * 256 + (int)threadIdx.x;
    for (int i = t0; i < n_l2; i += 8 * 256) {
      int t = i >> 4;
      int j = i & 15;
      wq[t * 32 + j]      = __float2half(w1_l2[i]);
      wq[t * 32 + 16 + j] = __float2half(w2_l2[i]);
    }
    return;
  }

  const int tid  = (int)threadIdx.x;
  const int lane = tid & 63;
  const int wv   = tid >> 6;      // 0..3
  const int r    = lane & 15;     // A row-in-tile / B col / D col
  const int q    = lane >> 4;     // k-subgroup 0..3
  const int node0 = (int)blockIdx.x * 64;

  // ---- B fragments: k = 32s + 8q + j, col = r ----
  f16x8 bf1[8], bf2[8];
#pragma unroll
  for (int s = 0; s < 8; ++s) {
#pragma unroll
    for (int j = 0; j < 8; ++j) {
      int k = 32 * s + 8 * q + j;
      bf1[s][j] = (_Float16)w1[k * L1_DIM + r];
      bf2[s][j] = (_Float16)w2[k * L1_DIM + r];
    }
  }

  // ---- A row pointer (clamped for tail block) ----
  int arow = node0 + wv * 16 + r;
  int ar = arow < n_nodes ? arow : (n_nodes - 1);
  const float* zrow = z + (size_t)ar * IN_DIM + 8 * q;

  f32x4 acc1 = {0.f, 0.f, 0.f, 0.f};
  f32x4 acc2 = {0.f, 0.f, 0.f, 0.f};

#pragma unroll
  for (int s = 0; s < 8; ++s) {
    float4 lo = *reinterpret_cast<const float4*>(zrow + 32 * s);
    float4 hi = *reinterpret_cast<const float4*>(zrow + 32 * s + 4);
    f16x8 af;
    af[0] = (_Float16)lo.x; af[1] = (_Float16)lo.y;
    af[2] = (_Float16)lo.z; af[3] = (_Float16)lo.w;
    af[4] = (_Float16)hi.x; af[5] = (_Float16)hi.y;
    af[6] = (_Float16)hi.z; af[7] = (_Float16)hi.w;
    acc1 = __builtin_amdgcn_mfma_f32_16x16x32_f16(af, bf1[s], acc1, 0, 0, 0);
    acc2 = __builtin_amdgcn_mfma_f32_16x16x32_f16(af, bf2[s], acc2, 0, 0, 0);
  }

  // ---- D layout: col = r, row = 4q + i -> node = node0 + 16wv + 4q + i ----
#pragma unroll
  for (int i = 0; i < 4; ++i) {
    int node = node0 + wv * 16 + 4 * q + i;
    if (node < n_nodes) {
      h1[(size_t)node * L1_DIM + r] = __float2half(fmaxf(acc1[i], 0.f));
      h2[(size_t)node * L1_DIM + r] = __float2half(fmaxf(acc2[i], 0.f));
    }
  }
}

// ---------------- edge kernel ----------------
// 2 lanes per edge (q = tid&1 owns row-half q). Per lane: 2 VMEM gathers
// (h1[src], h2[dst] halves — one instr covers a whole 32B row across the
// wave) + 2 ds_read_b128 from the LDS-staged interleaved w table (off the
// VMEM port). 8x fdot2, shfl_xor(1), even lane stores sigmoid.
// 62.5 KB LDS -> 2 blocks/CU; 512 thr -> 4 waves/SIMD; grid-stride.
union F4H { float4 f; __half2 h[4]; };

__global__ __launch_bounds__(512) void edge_kernel(
    const int* __restrict__ edge_index,  // [2][n_edges]
    const int* __restrict__ edge_type,   // [n_edges]
    const __half* __restrict__ h1,
    const __half* __restrict__ h2,
    const __half* __restrict__ wq,       // [1000][32] interleaved fp16
    float* __restrict__ out,
    int n_edges, int n_types) {
  __shared__ __align__(16) __half wl[N_ETYPE_MAX * 32];  // 62.5 KB

  const int tid = (int)threadIdx.x;

  // stage interleaved w table: coalesced float4 copies
  {
    const float4* src = reinterpret_cast<const float4*>(wq);
    float4* dst = reinterpret_cast<float4*>(wl);
    int nf4 = n_types * 4;  // 32 halves = 4 float4 per type
    for (int i = tid; i < nf4; i += 512) dst[i] = src[i];
  }
  __syncthreads();

  const int q = tid & 1;
  const int pair = tid >> 1;          // 0..255
  const int stride = (int)gridDim.x * 256;

  for (int e = (int)blockIdx.x * 256 + pair; e < n_edges; e += stride) {
    int src = edge_index[e];
    int dst = edge_index[n_edges + e];
    int t   = edge_type[e];

    F4H a, b, u, v;
    a.f = *reinterpret_cast<const float4*>(h1 + (size_t)src * L1_DIM + q * 8);
    b.f = *reinterpret_cast<const float4*>(h2 + (size_t)dst * L1_DIM + q * 8);
    u.f = *reinterpret_cast<const float4*>(wl + t * 32 + q * 8);
    v.f = *reinterpret_cast<const float4*>(wl + t * 32 + 16 + q * 8);

    float s = 0.f;
#if __has_builtin(__builtin_amdgcn_fdot2)
#pragma unroll
    for (int p = 0; p < 4; ++p) {
      s = __builtin_amdgcn_fdot2(a.h[p], u.h[p], s, false);
      s = __builtin_amdgcn_fdot2(b.h[p], v.h[p], s, false);
    }
#else
#pragma unroll
    for (int p = 0; p < 4; ++p) {
      float2 af = __half22float2(a.h[p]), uf = __half22float2(u.h[p]);
      float2 bf = __half22float2(b.h[p]), vf = __half22float2(v.h[p]);
      s = fmaf(af.x, uf.x, s); s = fmaf(af.y, uf.y, s);
      s = fmaf(bf.x, vf.x, s); s = fmaf(bf.y, vf.y, s);
    }
#endif

    s += __shfl_xor(s, 1);
    if (q == 0) {
      out[e] = 1.0f / (1.0f + __expf(-s));
    }
  }
}

extern "C" void kernel_launch(void* const* d_in, const int* in_sizes, int n_in,
                              void* d_out, int out_size, void* d_ws, size_t ws_size,
                              hipStream_t stream) {
  const float* z      = (const float*)d_in[0];
  const int* edge_idx = (const int*)d_in[1];
  const int* edge_typ = (const int*)d_in[2];
  const float* w1_l1  = (const float*)d_in[3];
  const float* w1_l2  = (const float*)d_in[4];
  const float* w2_l1  = (const float*)d_in[5];
  const float* w2_l2  = (const float*)d_in[6];
  float* out = (float*)d_out;

  int n_nodes = in_sizes[0] / IN_DIM;
  int n_edges = in_sizes[2];
  int n_l2    = in_sizes[4];          // 1000*16
  int n_types = n_l2 / L1_DIM;        // 1000

  __half* h1 = (__half*)d_ws;
  __half* h2 = h1 + (size_t)n_nodes * L1_DIM;
  __half* wq = h2 + (size_t)n_nodes * L1_DIM;   // [n_types][32]

  {
    int nblocks_proj = (n_nodes + 63) / 64;   // 782
    int grid = nblocks_proj + 8;              // +8 blocks: build wq
    proj_kernel<<<grid, 256, 0, stream>>>(z, w1_l1, w2_l1, w1_l2, w2_l2,
                                          h1, h2, wq,
                                          n_nodes, n_l2, nblocks_proj);
  }
  {
    edge_kernel<<<512, 512, 0, stream>>>(edge_idx, edge_typ, h1, h2, wq,
                                         out, n_edges, n_types);
  }
}